// Round 18
// baseline (163.771 us; speedup 1.0000x reference)
//
#include <hip/hip_runtime.h>
#include <math.h>

#define N_NODES 100000
#define E_EDGES 800000
#define NT 16                 // nodes per MFMA tile
#define NTILES (N_NODES / NT) // 6250
#define GRID 2048             // persistent blocks (8 per CU), 3-4 tiles each
#define OFF_MU 6400000L
#define OFF_LV 8000000L

typedef __attribute__((ext_vector_type(8))) short short8;
typedef __attribute__((ext_vector_type(4))) float f32x4;
typedef __attribute__((ext_vector_type(4))) float float4v;

// packed-weight fragment regions (units: shorts; each frag = 64 lanes * 8 = 512)
#define SW_AGG 0              // 8 frags  (4 jt x 2 kt)
#define SW_FUS 4096           // 16 frags (4 jt x 4 kt)
#define SW_W1  12288          // 8 frags
#define SW_W2  16384          // 4 frags  (frag 0,1 = W21; frag 2,3 = W22)
#define SW_W3  18432          // 4 frags  (4 jt x 1 kt, K padded 16->32)
#define SW_W4  20480          // 8 frags
#define SW_TOT 24576          // 48 KB of shorts

#define PW_OFF (1 << 20)      // packed weights at ws + 1 MB
#define XB_OFF (2 << 20)      // bf16 x at ws + 2 MB (12.8 MB)

// prep grid partition
#define PB_RS 3125            // build_row_start blocks (3125*256 = 800000)
#define PB_W  7               // pack_weights blocks
#define PB_X  3125            // pack_x blocks (100000*8 / 256)

__device__ __forceinline__ unsigned short f2bf(float f) {
    unsigned u = __float_as_uint(f);
    unsigned r = u + 0x7FFFu + ((u >> 16) & 1u);
    return (unsigned short)(r >> 16);
}
__device__ __forceinline__ float bf2f(unsigned short h) {
    return __uint_as_float(((unsigned)h) << 16);
}

// bf16 plane: [16 rows][64 cols], chunk-XOR swizzled (chunk = 8 shorts = 16B)
__device__ __forceinline__ int pidx(int row, int col) {
    const int c = ((col >> 3) ^ (row & 7));
    return row * 64 + c * 8 + (col & 7);
}

// pack one weight matrix into bf16 B-fragment layout (dst in global ws)
__device__ void stage_w(const float* __restrict__ W, int Ksrc, int NC,
                        int NKT, int NJT_local, int jt_off,
                        int rb, short* sw, int tid) {
    const int tot = NJT_local * NKT * 64;
    for (int s = tid; s < tot; s += 256) {
        int f = s >> 6, l = s & 63;
        int jtl = f / NKT, kt = f - jtl * NKT;
        int col = jtl * 16 + (l & 15);
        int k0 = kt * 32 + ((l >> 4) << 3);
        short8 hi;
        #pragma unroll
        for (int i = 0; i < 8; ++i) {
            float v = (k0 + i < Ksrc) ? W[(k0 + i) * NC + col] : 0.0f;
            hi[i] = (short)f2bf(v);
        }
        int fg = (jt_off + jtl) * NKT + kt;
        *(short8*)&sw[rb + fg * 512 + l * 8] = hi;
    }
}

// merged prep: [0,PB_RS) row_start | [PB_RS,+7) weights | rest pack_x
__global__ __launch_bounds__(256) void prep(
    const int* __restrict__ edge_dst, int* __restrict__ row_start,
    const float* __restrict__ W_agg, const float* __restrict__ W_fus,
    const float* __restrict__ W1,  const float* __restrict__ W21,
    const float* __restrict__ W22, const float* __restrict__ W3,
    const float* __restrict__ W4, short* __restrict__ gw,
    const float* __restrict__ x, short* __restrict__ xbf)
{
    const int b = blockIdx.x;
    const int tid = threadIdx.x;
    if (b < PB_RS) {
        const int e = b * 256 + tid;
        if (e >= E_EDGES) return;
        int d = edge_dst[e];
        int dprev = (e == 0) ? -1 : edge_dst[e - 1];
        for (int n = dprev + 1; n <= d; ++n) row_start[n] = e;
        if (e == E_EDGES - 1) {
            for (int n = d + 1; n <= N_NODES; ++n) row_start[n] = E_EDGES;
        }
    } else if (b < PB_RS + PB_W) {
        switch (b - PB_RS) {
            case 0: stage_w(W_agg, 64, 64, 2, 4, 0, SW_AGG, gw, tid); break;
            case 1: stage_w(W_fus, 128, 64, 4, 4, 0, SW_FUS, gw, tid); break;
            case 2: stage_w(W1,   64, 64, 2, 4, 0, SW_W1,  gw, tid); break;
            case 3: stage_w(W21,  64, 16, 2, 1, 0, SW_W2,  gw, tid); break;
            case 4: stage_w(W22,  64, 16, 2, 1, 1, SW_W2,  gw, tid); break;
            case 5: stage_w(W3,   16, 64, 1, 4, 0, SW_W3,  gw, tid); break;
            case 6: stage_w(W4,   64, 64, 2, 4, 0, SW_W4,  gw, tid); break;
        }
    } else {
        const int i = (b - PB_RS - PB_W) * 256 + tid;   // one short8 each
        if (i >= N_NODES * 8) return;
        const float4v a = ((const float4v*)x)[i * 2];
        const float4v c = ((const float4v*)x)[i * 2 + 1];
        short8 s;
        s[0] = (short)f2bf(a.x); s[1] = (short)f2bf(a.y);
        s[2] = (short)f2bf(a.z); s[3] = (short)f2bf(a.w);
        s[4] = (short)f2bf(c.x); s[5] = (short)f2bf(c.y);
        s[6] = (short)f2bf(c.z); s[7] = (short)f2bf(c.w);
        ((short8*)xbf)[i] = s;
    }
}

// A-frags (kt=0,1) for rows base..base+15 from prepacked bf16 row-major x
__device__ __forceinline__ void frags_from_xbf(const short* __restrict__ xbf,
                                               long base, int lane, short8* h) {
    const int row = lane & 15, ko = (lane >> 4) * 8;
    const short* r = xbf + (base + row) * 64;
    h[0] = *(const short8*)&r[ko];
    h[1] = *(const short8*)&r[32 + ko];
}

// A-frags from bf16 LDS plane: pure ds_read_b128
template<int NKT>
__device__ __forceinline__ void frags_from_planes(const short* phi, int lane,
                                                  short8* hi) {
    const int row = lane & 15;
    #pragma unroll
    for (int kt = 0; kt < NKT; ++kt) {
        const int c = kt * 4 + (lane >> 4);
        const int idx = row * 64 + ((c ^ (row & 7)) << 3);
        hi[kt] = *(const short8*)&phi[idx];
    }
}

// one jt-column-slab GEMM (16 rows x 16 cols), bf16 B from global packed weights
template<int NKT>
__device__ __forceinline__ f32x4 gemm_one(const short8* ah,
                                          const short* __restrict__ sw, int rb,
                                          int jt, float bias, int lane) {
    f32x4 acc = { bias, bias, bias, bias };
    #pragma unroll
    for (int kt = 0; kt < NKT; ++kt) {
        const short8 bhi = *(const short8*)&sw[rb + (jt * NKT + kt) * 512 + lane * 8];
        acc = __builtin_amdgcn_mfma_f32_16x16x32_bf16(ah[kt], bhi, acc, 0, 0, 0);
    }
    return acc;
}

// producer-side: relu + bf16 round + write into plane (4 values/lane)
__device__ __forceinline__ void write_slab_plane(short* phi, f32x4 c, int jt,
                                                 int lane, bool relu) {
    const int g = lane >> 4, cj = lane & 15;
    const int col = jt * 16 + cj;
    #pragma unroll
    for (int r = 0; r < 4; ++r) {
        float f = relu ? fmaxf(c[r], 0.0f) : c[r];
        phi[pidx(g * 4 + r, col)] = (short)f2bf(f);
    }
}

__device__ __forceinline__ float tree16(const float* v) {
    float a0 = (v[0] + v[1]) + (v[2] + v[3]);
    float a1 = (v[4] + v[5]) + (v[6] + v[7]);
    float a2 = (v[8] + v[9]) + (v[10] + v[11]);
    float a3 = (v[12] + v[13]) + (v[14] + v[15]);
    return (a0 + a1) + (a2 + a3);
}
__device__ __forceinline__ float tree8(const float* v) {
    return ((v[0] + v[1]) + (v[2] + v[3])) + ((v[4] + v[5]) + (v[6] + v[7]));
}

// Persistent blocks: 2048 blocks x 3-4 tiles. 1 tile = 16 nodes, 4 waves
// split 4 jt slabs. 6 barriers/tile (5 stage + 1 loop WAR). Dead gather
// lanes load x[0] unmasked; sum corrected by ndead*x0lane (1 fma/node).
__global__ __launch_bounds__(256, 8) void vae_top(
    const short* __restrict__ xbf,
    const int* __restrict__ edge_src,
    const float* __restrict__ eps,
    const float* __restrict__ b_agg, const float* __restrict__ b_fus,
    const float* __restrict__ b1,  const float* __restrict__ b21,
    const float* __restrict__ b22, const float* __restrict__ b3,
    const float* __restrict__ b4,
    const short* __restrict__ gw,
    const int* __restrict__ row_start,
    float* __restrict__ out)
{
    __shared__ __align__(16) short sA[1024];        // bf16 act plane (ping), 2 KB
    __shared__ __align__(16) short sB[1024];        // (pong)
    __shared__ __align__(16) short sZ[4 * 16 * 24]; // wave-private z, stride 24

    const int tid  = threadIdx.x;
    const int lane = tid & 63;
    const int wid  = tid >> 6;       // wave id == jt slab
    const int cj = lane & 15, g = lane >> 4;

    // hoisted per-block constants
    const float bja = b_agg[wid * 16 + cj];
    const float bjf = b_fus[wid * 16 + cj];
    const float bj1 = b1[wid * 16 + cj];
    const float bj3 = b3[wid * 16 + cj];
    const float bj4 = b4[wid * 16 + cj];
    const float b21l = b21[cj];
    const float b22l = b22[cj];

    const unsigned short* xbu = (const unsigned short*)xbf;
    const float x0lane = bf2f(xbu[lane]);   // dead-lane correction value
    short* sZw = sZ + wid * (16 * 24);

    for (int t = blockIdx.x; t < NTILES; t += GRID) {
        const long base = (long)t * NT;

        // ---- gather: each wave does 4 nodes; deg-adaptive batch ----
        {
            const int rsv = row_start[(int)base + (lane < 17 ? lane : 16)];
            const int W0 = __builtin_amdgcn_readlane(rsv, wid * 4);
            int p0 = W0 + lane;      p0 = p0 < E_EDGES ? p0 : E_EDGES - 1;
            int p1 = W0 + 64 + lane; p1 = p1 < E_EDGES ? p1 : E_EDGES - 1;
            const int iv0 = edge_src[p0];
            const int iv1 = edge_src[p1];

            #pragma unroll
            for (int q = 0; q < 4; ++q) {
                const int node = wid * 4 + q;
                const int e0 = __builtin_amdgcn_readlane(rsv, node);
                const int e1 = __builtin_amdgcn_readlane(rsv, node + 1);
                const int deg = e1 - e0;
                const int te0 = e0 - W0;
                float sum;
                if (deg <= 8 && te0 + 7 < 128) {
                    float v[8];
                    #pragma unroll
                    for (int i = 0; i < 8; ++i) {
                        const int te = te0 + i;
                        const int vsel = (te & 64) ? iv1 : iv0;
                        int ix = __builtin_amdgcn_readlane(vsel, te & 63);
                        ix = (i < deg) ? ix : 0;        // uniform: s_cselect
                        v[i] = bf2f(xbu[(long)ix * 64 + lane]);
                    }
                    sum = tree8(v) - (float)(8 - deg) * x0lane;
                } else if (te0 + 15 < 128) {
                    float v[16];
                    #pragma unroll
                    for (int i = 0; i < 16; ++i) {
                        const int te = te0 + i;
                        const int vsel = (te & 64) ? iv1 : iv0;
                        int ix = __builtin_amdgcn_readlane(vsel, te & 63);
                        ix = (i < deg) ? ix : 0;
                        v[i] = bf2f(xbu[(long)ix * 64 + lane]);
                    }
                    int dead = 16 - deg; dead = dead > 0 ? dead : 0;
                    sum = tree16(v) - (float)dead * x0lane;
                    for (int e = e0 + 16; e < e1; ++e)          // rare deg>16
                        sum += bf2f(xbu[(long)edge_src[e] * 64 + lane]);
                } else {
                    float v[16];
                    #pragma unroll
                    for (int i = 0; i < 16; ++i) {
                        const int ee = e0 + i;
                        const int ec = ee < E_EDGES ? ee : E_EDGES - 1;
                        int ix = edge_src[ec];
                        ix = (i < deg) ? ix : 0;
                        v[i] = bf2f(xbu[(long)ix * 64 + lane]);
                    }
                    int dead = 16 - deg; dead = dead > 0 ? dead : 0;
                    sum = tree16(v) - (float)dead * x0lane;
                    for (int e = e0 + 16; e < e1; ++e)
                        sum += bf2f(xbu[(long)edge_src[e] * 64 + lane]);
                }
                const float avg = sum / fmaxf((float)deg, 1.0f);
                sA[pidx(node, lane)] = (short)f2bf(avg);
            }
        }
        __syncthreads();                                     // bar 1

        short8 ah[4];
        f32x4 c;

        // ---- ne = relu(avg @ W_agg + b_agg): A -> B ----
        frags_from_planes<2>(sA, lane, ah);
        c = gemm_one<2>(ah, gw, SW_AGG, wid, bja, lane);
        write_slab_plane(sB, c, wid, lane, true);
        __syncthreads();                                     // bar 2

        // ---- xf = relu([x, ne] @ W_fus + b_fus): xbf(global) + B -> A ----
        frags_from_xbf(xbf, base, lane, ah);                 // kt 0,1 (x)
        frags_from_planes<2>(sB, lane, ah + 2);              // kt 2,3 (ne)
        c = gemm_one<4>(ah, gw, SW_FUS, wid, bjf, lane);
        write_slab_plane(sA, c, wid, lane, true);
        __syncthreads();                                     // bar 3

        // ---- h1 = relu(xf @ W1 + b1): A -> B ----
        frags_from_planes<2>(sA, lane, ah);
        c = gemm_one<2>(ah, gw, SW_W1, wid, bj1, lane);
        write_slab_plane(sB, c, wid, lane, true);
        __syncthreads();                                     // bar 4

        // ---- mu/lv/z replicated in ALL waves; z -> wave-private scratch ----
        {
            frags_from_planes<2>(sB, lane, ah);              // h1 frags
            const f32x4 cmu = gemm_one<2>(ah, gw, SW_W2, 0, b21l, lane);
            const f32x4 clv = gemm_one<2>(ah, gw, SW_W2, 1, b22l, lane);
            #pragma unroll
            for (int r = 0; r < 4; ++r) {
                const long node = base + g * 4 + r;
                if (wid == 0) {
                    out[OFF_MU + node * 16 + cj] = cmu[r];
                    out[OFF_LV + node * 16 + cj] = clv[r];
                }
                const float z = cmu[r] + eps[node * 16 + cj] * __expf(0.5f * clv[r]);
                sZw[(g * 4 + r) * 24 + cj] = (short)f2bf(z);  // wave-private
            }
        }
        // no barrier: each wave reads only its own z scratch

        // ---- h3 = relu(z @ W3 + b3): sZw (K padded to 32) -> A ----
        {
            short8 zh = {0,0,0,0,0,0,0,0};
            if (lane < 32) {
                const int row = lane & 15;
                const int ch = lane >> 4;                    // chunk 0/1
                zh = *(const short8*)&sZw[row * 24 + ch * 8];
            }
            c = gemm_one<1>(&zh, gw, SW_W3, wid, bj3, lane);
        }
        write_slab_plane(sA, c, wid, lane, true);            // sA dead since bar 4
        __syncthreads();                                     // bar 5

        // ---- recon = sigmoid(h3 @ W4 + b4): A -> out ----
        frags_from_planes<2>(sA, lane, ah);
        c = gemm_one<2>(ah, gw, SW_W4, wid, bj4, lane);
        #pragma unroll
        for (int r = 0; r < 4; ++r) {
            const float s = 1.0f / (1.0f + __expf(-c[r]));
            out[(base + g * 4 + r) * 64 + wid * 16 + cj] = s;
        }
        __syncthreads();   // bar 6: protect sA/sB reuse by next tile's gather
    }
}

extern "C" void kernel_launch(void* const* d_in, const int* in_sizes, int n_in,
                              void* d_out, int out_size, void* d_ws, size_t ws_size,
                              hipStream_t stream) {
    const float* x        = (const float*)d_in[0];
    const int*   edge_src = (const int*)  d_in[1];
    const int*   edge_dst = (const int*)  d_in[2];
    const float* eps      = (const float*)d_in[3];
    const float* W_agg    = (const float*)d_in[4];
    const float* b_agg    = (const float*)d_in[5];
    const float* W_fus    = (const float*)d_in[6];
    const float* b_fus    = (const float*)d_in[7];
    const float* W1       = (const float*)d_in[8];
    const float* b1       = (const float*)d_in[9];
    const float* W21      = (const float*)d_in[10];
    const float* b21      = (const float*)d_in[11];
    const float* W22      = (const float*)d_in[12];
    const float* b22      = (const float*)d_in[13];
    const float* W3       = (const float*)d_in[14];
    const float* b3       = (const float*)d_in[15];
    const float* W4       = (const float*)d_in[16];
    const float* b4       = (const float*)d_in[17];
    float* out = (float*)d_out;

    // ws: row_start @0 (400KB) | packed weights @1MB (48KB) | bf16 x @2MB (12.8MB)
    int*   row_start = (int*)d_ws;
    short* gw        = (short*)((char*)d_ws + PW_OFF);
    short* xbf       = (short*)((char*)d_ws + XB_OFF);

    prep<<<PB_RS + PB_W + PB_X, 256, 0, stream>>>(edge_dst, row_start,
                                                  W_agg, W_fus, W1, W21, W22, W3, W4,
                                                  gw, x, xbf);
    vae_top<<<GRID, 256, 0, stream>>>(xbf, edge_src, eps,
                                      b_agg, b_fus, b1, b21, b22, b3, b4,
                                      gw, row_start, out);
}

// Round 19
// 57.130 us; speedup vs baseline: 2.8666x; 2.8666x over previous
//
#include <hip/hip_runtime.h>
#include <math.h>

#define N_NODES 100000
#define E_EDGES 800000
#define NT 16                 // nodes per MFMA tile
#define NTILES (N_NODES / NT) // 6250 (one block per tile, 4 waves split the jt cols)
#define OFF_MU 6400000L
#define OFF_LV 8000000L

typedef __attribute__((ext_vector_type(8))) short short8;
typedef __attribute__((ext_vector_type(4))) float f32x4;
typedef __attribute__((ext_vector_type(4))) float float4v;

// packed-weight fragment regions (units: shorts; each frag = 64 lanes * 8 = 512)
#define SW_AGG 0              // 8 frags  (4 jt x 2 kt)
#define SW_FUS 4096           // 16 frags (4 jt x 4 kt)
#define SW_W1  12288          // 8 frags
#define SW_W2  16384          // 4 frags  (frag 0,1 = W21; frag 2,3 = W22)
#define SW_W3  18432          // 4 frags  (4 jt x 1 kt, K padded 16->32)
#define SW_W4  20480          // 8 frags
#define SW_TOT 24576          // 48 KB of shorts

#define PW_OFF (1 << 20)      // packed weights at ws + 1 MB
#define XB_OFF (2 << 20)      // bf16 x at ws + 2 MB (12.8 MB)

// prep grid partition
#define PB_RS 3125            // build_row_start blocks (3125*256 = 800000)
#define PB_W  7               // pack_weights blocks
#define PB_X  3125            // pack_x blocks (100000*8 / 256)

__device__ __forceinline__ unsigned short f2bf(float f) {
    unsigned u = __float_as_uint(f);
    unsigned r = u + 0x7FFFu + ((u >> 16) & 1u);
    return (unsigned short)(r >> 16);
}
__device__ __forceinline__ float bf2f(unsigned short h) {
    return __uint_as_float(((unsigned)h) << 16);
}

// bf16 plane: [16 rows][64 cols], chunk-XOR swizzled (chunk = 8 shorts = 16B)
__device__ __forceinline__ int pidx(int row, int col) {
    const int c = ((col >> 3) ^ (row & 7));
    return row * 64 + c * 8 + (col & 7);
}

// pack one weight matrix into bf16 B-fragment layout (dst in global ws)
__device__ void stage_w(const float* __restrict__ W, int Ksrc, int NC,
                        int NKT, int NJT_local, int jt_off,
                        int rb, short* sw, int tid) {
    const int tot = NJT_local * NKT * 64;
    for (int s = tid; s < tot; s += 256) {
        int f = s >> 6, l = s & 63;
        int jtl = f / NKT, kt = f - jtl * NKT;
        int col = jtl * 16 + (l & 15);
        int k0 = kt * 32 + ((l >> 4) << 3);
        short8 hi;
        #pragma unroll
        for (int i = 0; i < 8; ++i) {
            float v = (k0 + i < Ksrc) ? W[(k0 + i) * NC + col] : 0.0f;
            hi[i] = (short)f2bf(v);
        }
        int fg = (jt_off + jtl) * NKT + kt;
        *(short8*)&sw[rb + fg * 512 + l * 8] = hi;
    }
}

// merged prep: [0,PB_RS) row_start | [PB_RS,+7) weights | rest pack_x
__global__ __launch_bounds__(256) void prep(
    const int* __restrict__ edge_dst, int* __restrict__ row_start,
    const float* __restrict__ W_agg, const float* __restrict__ W_fus,
    const float* __restrict__ W1,  const float* __restrict__ W21,
    const float* __restrict__ W22, const float* __restrict__ W3,
    const float* __restrict__ W4, short* __restrict__ gw,
    const float* __restrict__ x, short* __restrict__ xbf)
{
    const int b = blockIdx.x;
    const int tid = threadIdx.x;
    if (b < PB_RS) {
        const int e = b * 256 + tid;
        if (e >= E_EDGES) return;
        int d = edge_dst[e];
        int dprev = (e == 0) ? -1 : edge_dst[e - 1];
        for (int n = dprev + 1; n <= d; ++n) row_start[n] = e;
        if (e == E_EDGES - 1) {
            for (int n = d + 1; n <= N_NODES; ++n) row_start[n] = E_EDGES;
        }
    } else if (b < PB_RS + PB_W) {
        switch (b - PB_RS) {
            case 0: stage_w(W_agg, 64, 64, 2, 4, 0, SW_AGG, gw, tid); break;
            case 1: stage_w(W_fus, 128, 64, 4, 4, 0, SW_FUS, gw, tid); break;
            case 2: stage_w(W1,   64, 64, 2, 4, 0, SW_W1,  gw, tid); break;
            case 3: stage_w(W21,  64, 16, 2, 1, 0, SW_W2,  gw, tid); break;
            case 4: stage_w(W22,  64, 16, 2, 1, 1, SW_W2,  gw, tid); break;
            case 5: stage_w(W3,   16, 64, 1, 4, 0, SW_W3,  gw, tid); break;
            case 6: stage_w(W4,   64, 64, 2, 4, 0, SW_W4,  gw, tid); break;
        }
    } else {
        const int i = (b - PB_RS - PB_W) * 256 + tid;   // one short8 each
        if (i >= N_NODES * 8) return;
        const float4v a = ((const float4v*)x)[i * 2];
        const float4v c = ((const float4v*)x)[i * 2 + 1];
        short8 s;
        s[0] = (short)f2bf(a.x); s[1] = (short)f2bf(a.y);
        s[2] = (short)f2bf(a.z); s[3] = (short)f2bf(a.w);
        s[4] = (short)f2bf(c.x); s[5] = (short)f2bf(c.y);
        s[6] = (short)f2bf(c.z); s[7] = (short)f2bf(c.w);
        ((short8*)xbf)[i] = s;
    }
}

// A-frags (kt=0,1) for rows base..base+15 from prepacked bf16 row-major x
__device__ __forceinline__ void frags_from_xbf(const short* __restrict__ xbf,
                                               long base, int lane, short8* h) {
    const int row = lane & 15, ko = (lane >> 4) * 8;
    const short* r = xbf + (base + row) * 64;
    h[0] = *(const short8*)&r[ko];
    h[1] = *(const short8*)&r[32 + ko];
}

// A-frags from bf16 LDS plane: pure ds_read_b128
template<int NKT>
__device__ __forceinline__ void frags_from_planes(const short* phi, int lane,
                                                  short8* hi) {
    const int row = lane & 15;
    #pragma unroll
    for (int kt = 0; kt < NKT; ++kt) {
        const int c = kt * 4 + (lane >> 4);
        const int idx = row * 64 + ((c ^ (row & 7)) << 3);
        hi[kt] = *(const short8*)&phi[idx];
    }
}

// one jt-column-slab GEMM (16 rows x 16 cols), bf16 B from global packed weights
template<int NKT>
__device__ __forceinline__ f32x4 gemm_one(const short8* ah,
                                          const short* __restrict__ sw, int rb,
                                          int jt, float bias, int lane) {
    f32x4 acc = { bias, bias, bias, bias };
    #pragma unroll
    for (int kt = 0; kt < NKT; ++kt) {
        const short8 bhi = *(const short8*)&sw[rb + (jt * NKT + kt) * 512 + lane * 8];
        acc = __builtin_amdgcn_mfma_f32_16x16x32_bf16(ah[kt], bhi, acc, 0, 0, 0);
    }
    return acc;
}

// producer-side: relu + bf16 round + write into plane (4 values/lane)
__device__ __forceinline__ void write_slab_plane(short* phi, f32x4 c, int jt,
                                                 int lane, bool relu) {
    const int g = lane >> 4, cj = lane & 15;
    const int col = jt * 16 + cj;
    #pragma unroll
    for (int r = 0; r < 4; ++r) {
        float f = relu ? fmaxf(c[r], 0.0f) : c[r];
        phi[pidx(g * 4 + r, col)] = (short)f2bf(f);
    }
}

__device__ __forceinline__ float tree16(const float* v) {
    float a0 = (v[0] + v[1]) + (v[2] + v[3]);
    float a1 = (v[4] + v[5]) + (v[6] + v[7]);
    float a2 = (v[8] + v[9]) + (v[10] + v[11]);
    float a3 = (v[12] + v[13]) + (v[14] + v[15]);
    return (a0 + a1) + (a2 + a3);
}
__device__ __forceinline__ float tree8(const float* v) {
    return ((v[0] + v[1]) + (v[2] + v[3])) + ((v[4] + v[5]) + (v[6] + v[7]));
}

// 1 block = 1 tile (16 nodes); 4 waves split the 4 jt column slabs.
// r17 structure verbatim (best: 57.6us) + bijective XCD tile swizzle (m204):
// each XCD gets a contiguous slice of tiles -> L2 locality for the
// sequential row_start/edge_src/xbf streams. No liveness change.
__global__ __launch_bounds__(256, 8) void vae_top(
    const short* __restrict__ xbf,
    const int* __restrict__ edge_src,
    const float* __restrict__ eps,
    const float* __restrict__ b_agg, const float* __restrict__ b_fus,
    const float* __restrict__ b1,  const float* __restrict__ b21,
    const float* __restrict__ b22, const float* __restrict__ b3,
    const float* __restrict__ b4,
    const short* __restrict__ gw,
    const int* __restrict__ row_start,
    float* __restrict__ out)
{
    __shared__ __align__(16) short sA[1024];        // bf16 act plane (ping), 2 KB
    __shared__ __align__(16) short sB[1024];        // (pong)
    __shared__ __align__(16) short sZ[4 * 16 * 24]; // wave-private z, stride 24

    const int tid  = threadIdx.x;
    const int lane = tid & 63;
    const int wid  = tid >> 6;       // wave id == jt slab

    // bijective XCD-aware tile swizzle: xcd = bid%8 gets contiguous tiles
    const int bid = blockIdx.x;
    const int xcd = bid & 7, loc = bid >> 3;
    const int qq = NTILES / 8, rr = NTILES % 8;   // 781, 2
    const int t = (xcd < rr ? xcd * (qq + 1) : rr * (qq + 1) + (xcd - rr) * qq) + loc;

    const long base = (long)t * NT;
    const int cj = lane & 15, g = lane >> 4;

    const float bja = b_agg[wid * 16 + cj];
    const float bjf = b_fus[wid * 16 + cj];
    const float bj1 = b1[wid * 16 + cj];
    const float bj3 = b3[wid * 16 + cj];
    const float bj4 = b4[wid * 16 + cj];
    const float b21l = b21[cj];
    const float b22l = b22[cj];

    const unsigned short* xbu = (const unsigned short*)xbf;
    short* sZw = sZ + wid * (16 * 24);

    // ---- gather: each wave does 4 nodes; deg-adaptive masked batch ----
    {
        const int rsv = row_start[(int)base + (lane < 17 ? lane : 16)];
        const int W0 = __builtin_amdgcn_readlane(rsv, wid * 4);
        int p0 = W0 + lane;      p0 = p0 < E_EDGES ? p0 : E_EDGES - 1;
        int p1 = W0 + 64 + lane; p1 = p1 < E_EDGES ? p1 : E_EDGES - 1;
        const int iv0 = edge_src[p0];
        const int iv1 = edge_src[p1];

        #pragma unroll
        for (int q = 0; q < 4; ++q) {
            const int node = wid * 4 + q;
            const int e0 = __builtin_amdgcn_readlane(rsv, node);
            const int e1 = __builtin_amdgcn_readlane(rsv, node + 1);
            const int deg = e1 - e0;
            const int te0 = e0 - W0;
            float sum;
            if (deg <= 8 && te0 + 7 < 128) {
                float v[8];
                #pragma unroll
                for (int i = 0; i < 8; ++i) {
                    const int te = te0 + i;
                    const int vsel = (te & 64) ? iv1 : iv0;
                    int ix = __builtin_amdgcn_readlane(vsel, te & 63);
                    const bool live = i < deg;
                    ix = live ? ix : 0;
                    float tv = bf2f(xbu[(long)ix * 64 + lane]);
                    v[i] = live ? tv : 0.0f;
                }
                sum = tree8(v);
            } else if (te0 + 15 < 128) {
                float v[16];
                #pragma unroll
                for (int i = 0; i < 16; ++i) {
                    const int te = te0 + i;
                    const int vsel = (te & 64) ? iv1 : iv0;
                    int ix = __builtin_amdgcn_readlane(vsel, te & 63);
                    const bool live = i < deg;
                    ix = live ? ix : 0;
                    float tv = bf2f(xbu[(long)ix * 64 + lane]);
                    v[i] = live ? tv : 0.0f;
                }
                sum = tree16(v);
                for (int e = e0 + 16; e < e1; ++e)          // rare (deg>16)
                    sum += bf2f(xbu[(long)edge_src[e] * 64 + lane]);
            } else {
                float v[16];
                #pragma unroll
                for (int i = 0; i < 16; ++i) {
                    const int ee = e0 + i;
                    const bool live = ee < e1;
                    const int ec = ee < E_EDGES ? ee : E_EDGES - 1;
                    int ix = edge_src[ec];
                    ix = live ? ix : 0;
                    float tv = bf2f(xbu[(long)ix * 64 + lane]);
                    v[i] = live ? tv : 0.0f;
                }
                sum = tree16(v);
                for (int e = e0 + 16; e < e1; ++e)
                    sum += bf2f(xbu[(long)edge_src[e] * 64 + lane]);
            }
            const float avg = sum / fmaxf((float)deg, 1.0f);
            sA[pidx(node, lane)] = (short)f2bf(avg);
        }
    }
    __syncthreads();                                     // bar 1

    short8 ah[4];
    f32x4 c;

    // ---- ne = relu(avg @ W_agg + b_agg): A -> B ----
    frags_from_planes<2>(sA, lane, ah);
    c = gemm_one<2>(ah, gw, SW_AGG, wid, bja, lane);
    write_slab_plane(sB, c, wid, lane, true);
    __syncthreads();                                     // bar 2

    // ---- xf = relu([x, ne] @ W_fus + b_fus): xbf(global) + B -> A ----
    frags_from_xbf(xbf, base, lane, ah);                 // kt 0,1 (x)
    frags_from_planes<2>(sB, lane, ah + 2);              // kt 2,3 (ne)
    c = gemm_one<4>(ah, gw, SW_FUS, wid, bjf, lane);
    write_slab_plane(sA, c, wid, lane, true);
    __syncthreads();                                     // bar 3

    // ---- h1 = relu(xf @ W1 + b1): A -> B ----
    frags_from_planes<2>(sA, lane, ah);
    c = gemm_one<2>(ah, gw, SW_W1, wid, bj1, lane);
    write_slab_plane(sB, c, wid, lane, true);
    __syncthreads();                                     // bar 4

    // ---- mu/lv/z replicated in ALL waves; z -> wave-private scratch ----
    {
        frags_from_planes<2>(sB, lane, ah);              // h1 frags
        const f32x4 cmu = gemm_one<2>(ah, gw, SW_W2, 0, b21l, lane);
        const f32x4 clv = gemm_one<2>(ah, gw, SW_W2, 1, b22l, lane);
        #pragma unroll
        for (int r = 0; r < 4; ++r) {
            const long node = base + g * 4 + r;
            if (wid == 0) {
                out[OFF_MU + node * 16 + cj] = cmu[r];
                out[OFF_LV + node * 16 + cj] = clv[r];
            }
            const float z = cmu[r] + eps[node * 16 + cj] * __expf(0.5f * clv[r]);
            sZw[(g * 4 + r) * 24 + cj] = (short)f2bf(z);  // wave-private
        }
    }
    // no barrier: each wave reads only its own z scratch (in-wave lgkmcnt)

    // ---- h3 = relu(z @ W3 + b3): sZw (K padded to 32) -> A ----
    {
        short8 zh = {0,0,0,0,0,0,0,0};
        if (lane < 32) {
            const int row = lane & 15;
            const int ch = lane >> 4;                    // chunk 0/1 (cols 0..15)
            zh = *(const short8*)&sZw[row * 24 + ch * 8];
        }
        c = gemm_one<1>(&zh, gw, SW_W3, wid, bj3, lane);
    }
    write_slab_plane(sA, c, wid, lane, true);            // sA dead since bar 4
    __syncthreads();                                     // bar 5

    // ---- recon = sigmoid(h3 @ W4 + b4): A -> out ----
    frags_from_planes<2>(sA, lane, ah);
    c = gemm_one<2>(ah, gw, SW_W4, wid, bj4, lane);
    #pragma unroll
    for (int r = 0; r < 4; ++r) {
        const float s = 1.0f / (1.0f + __expf(-c[r]));
        out[(base + g * 4 + r) * 64 + wid * 16 + cj] = s;
    }
}

extern "C" void kernel_launch(void* const* d_in, const int* in_sizes, int n_in,
                              void* d_out, int out_size, void* d_ws, size_t ws_size,
                              hipStream_t stream) {
    const float* x        = (const float*)d_in[0];
    const int*   edge_src = (const int*)  d_in[1];
    const int*   edge_dst = (const int*)  d_in[2];
    const float* eps      = (const float*)d_in[3];
    const float* W_agg    = (const float*)d_in[4];
    const float* b_agg    = (const float*)d_in[5];
    const float* W_fus    = (const float*)d_in[6];
    const float* b_fus    = (const float*)d_in[7];
    const float* W1       = (const float*)d_in[8];
    const float* b1       = (const float*)d_in[9];
    const float* W21      = (const float*)d_in[10];
    const float* b21      = (const float*)d_in[11];
    const float* W22      = (const float*)d_in[12];
    const float* b22      = (const float*)d_in[13];
    const float* W3       = (const float*)d_in[14];
    const float* b3       = (const float*)d_in[15];
    const float* W4       = (const float*)d_in[16];
    const float* b4       = (const float*)d_in[17];
    float* out = (float*)d_out;

    // ws: row_start @0 (400KB) | packed weights @1MB (48KB) | bf16 x @2MB (12.8MB)
    int*   row_start = (int*)d_ws;
    short* gw        = (short*)((char*)d_ws + PW_OFF);
    short* xbf       = (short*)((char*)d_ws + XB_OFF);

    prep<<<PB_RS + PB_W + PB_X, 256, 0, stream>>>(edge_dst, row_start,
                                                  W_agg, W_fus, W1, W21, W22, W3, W4,
                                                  gw, x, xbf);
    vae_top<<<NTILES, 256, 0, stream>>>(xbf, edge_src, eps,
                                        b_agg, b_fus, b1, b21, b22, b3, b4,
                                        gw, row_start, out);
}